// Round 10
// baseline (1926.540 us; speedup 1.0000x reference)
//
#include <hip/hip_runtime.h>
#include <stdint.h>
#include <string.h>

// Problem dims (fixed by the reference)
#define BDIM   4096
#define INDIM  1024
#define XDIM   2048
#define OUTDIM 512
#define MCH    (BDIM / 16)   // 256 row-chunks along M for packed activations

#define LO_SCALE 2048.0f         // 2^11: lifts fp16 lo-plane out of subnormals
#define INV_LO_SCALE (1.0f / 2048.0f)

typedef _Float16 f16x8 __attribute__((ext_vector_type(8)));
typedef float f32x4 __attribute__((ext_vector_type(4)));

__device__ __forceinline__ unsigned short h2u(_Float16 h) {
  unsigned short u;
  memcpy(&u, &h, 2);
  return u;
}

// split f32 into hi fp16 + scaled-lo fp16 (combined ~22 mantissa bits)
__device__ __forceinline__ void split_h(float v, unsigned short& h,
                                        unsigned short& l) {
  _Float16 hh = (_Float16)v;                       // RTNE
  float r = v - (float)hh;                         // exact
  _Float16 ll = (_Float16)(r * LO_SCALE);          // |r|*2^11 <= |v|, no inf
  h = h2u(hh);
  l = h2u(ll);
}

// async global->LDS, 16B per lane; LDS dest wave-uniform base + lane*16
__device__ __forceinline__ void gld_lds16(const void* g, void* l) {
  __builtin_amdgcn_global_load_lds(
      (const __attribute__((address_space(1))) uint32_t*)g,
      (__attribute__((address_space(3))) uint32_t*)l, 16, 0, 0);
}

// fused RandomActivation + clip (relu/sigmoid/tanh/leaky(.1)/selu), libm-grade
__device__ __forceinline__ float rand_act(float v, int a, float mo) {
  float r;
  if (a == 0) {
    r = fmaxf(v, 0.0f);
  } else if (a == 1) {
    r = 1.0f / (1.0f + expf(-v));
  } else if (a == 2) {
    r = tanhf(v);
  } else if (a == 3) {
    r = (v >= 0.0f) ? v : 0.1f * v;
  } else {  // selu (matches jax: scale * where(v>0, v, alpha*expm1(v)))
    r = (v > 0.0f) ? 1.0507009873554805f * v
                   : 1.7580993408473766f * expm1f(v);
  }
  return fminf(r, mo);
}

// ---------------------------------------------------------------------------
// PACKED LAYOUT (R9-verified): tensor X[rows][K] stored as
//   packed[k/32][row/16][lane(64)][8 halfs],  lane = quad*16 + m16 holding
//   X[chunkrow*16 + m16][kstep*32 + quad*8 + j].
// Each (kstep,chunk) = contiguous 1 KB: staging DMA is consecutive-lane-
// contiguous (coalesced) AND compute ds_read_b128 is contiguous (0 bank
// conflicts). Concat along K = packed tensors back-to-back.
// ---------------------------------------------------------------------------

// x[BDIM][Kin] f32 row-major -> packed hi/lo planes. grid(Kin/32, BDIM/64)x256
__global__ void pack_x(const float* __restrict__ s,
                       unsigned short* __restrict__ dh,
                       unsigned short* __restrict__ dl, int Kin) {
  int ks = blockIdx.x;
  int mblk = blockIdx.y;
  int cc = threadIdx.x >> 6;        // chunk within 64-row group
  int lane = threadIdx.x & 63;
  int m16 = lane & 15, quad = lane >> 4;
  int row = mblk * 64 + cc * 16 + m16;
  const float* src = s + (size_t)row * Kin + ks * 32 + quad * 8;
  size_t o = ((size_t)ks * MCH + mblk * 4 + cc) * 512 + lane * 8;
#pragma unroll
  for (int j = 0; j < 8; j++) {
    unsigned short h, l;
    split_h(src[j], h, l);
    dh[o + j] = h;
    dl[o + j] = l;
  }
}

// W[K][N] f32 row-major -> packed-BT hi/lo (rows=N, Kdim=K).
// grid(N/32, K/32), block(32,8).
__global__ void pack_w(const float* __restrict__ W,
                       unsigned short* __restrict__ dh,
                       unsigned short* __restrict__ dl, int K, int N) {
  __shared__ float t[32][33];       // t[k'][n']
  int n0 = blockIdx.x * 32, k0 = blockIdx.y * 32;
  int tx = threadIdx.x, ty = threadIdx.y;
#pragma unroll
  for (int i = 0; i < 32; i += 8)
    t[ty + i][tx] = W[(size_t)(k0 + ty + i) * N + n0 + tx];
  __syncthreads();
  int tt = ty * 32 + tx;            // 0..255
  int ci = tt >> 7;                 // n-chunk 0/1
  int rem = tt & 127;
  int lane = rem >> 1;
  int j4 = (rem & 1) * 4;
  int m16 = lane & 15, quad = lane >> 4;
  size_t o = ((size_t)(k0 >> 5) * (N >> 4) + (n0 >> 4) + ci) * 512 +
             lane * 8 + j4;
#pragma unroll
  for (int jj = 0; jj < 4; jj++) {
    float v = t[quad * 8 + j4 + jj][ci * 16 + m16];
    unsigned short h, l;
    split_h(v, h, l);
    dh[o + jj] = h;
    dl[o + jj] = l;
  }
}

// C[M,N] = act( A[M,K] @ BT[N,K]^T + bias ), split-fp16 (3-term) precision.
// acc1 = hi*hi; acc2 = hi*lo' + lo'*hi at scale 2^11. Final = acc1+acc2/2^11.
//
// Round-10 structure = R9 + BK=64 macro-steps (barrier-amortization):
//  - each LDS buffer holds TWO packed 32-K sub-steps (16 KB); one
//    __syncthreads per 64-K macro-step -> half the barriers, 48 MFMAs of
//    compute overlapping each barrier drain (R9: 24).
//  - B: global -> VGPR from packed 1-KB chunks, loaded JUST-IN-TIME one
//    sub-step ahead (two 16-reg sets rotate; VGPR count stays ~R9 so the
//    4-waves/SIMD occupancy point is preserved: acc 64 AGPR + ~64-80 VGPR).
//  - A staged via global_load_lds from packed chunks (coalesced + conflict-
//    free, R9-verified).
// Block tile 64x128, 4 waves (wave-tile 64x32). Grid (N/128, M/64) ->
// 1024 blocks = 4 blocks/CU. LDS 2 x 16 KB = 32 KB.
template <bool OUT_F16>
__global__ __launch_bounds__(256, 4) void gemm_split_act(
    const short* __restrict__ A1h, const short* __restrict__ A1l,
    const short* __restrict__ A2h, const short* __restrict__ A2l,
    const short* __restrict__ BTh, const short* __restrict__ BTl,
    const float* __restrict__ bias, const float* __restrict__ mo,
    const int* __restrict__ aid, unsigned short* __restrict__ Ch,
    unsigned short* __restrict__ Cl, float* __restrict__ Cf, int N, int K,
    int Ksplit) {
  __shared__ short lA0[16 * 512];  // 16 KB: [sub(2)][chunk 0-3 hi, 4-7 lo]
  __shared__ short lA1[16 * 512];

  const int tid = threadIdx.x;
  const int lane = tid & 63;
  const int wave = tid >> 6;        // 0..3 = n-strip of wave
  const int m16 = lane & 15, quad = lane >> 4;

  const int blockN = blockIdx.x * 128;
  const int blockM = blockIdx.y * 64;

  f32x4 acc1[4][2];  // hi*hi
  f32x4 acc2[4][2];  // (hi*lo' + lo'*hi), scale 2^11
#pragma unroll
  for (int i = 0; i < 4; i++)
#pragma unroll
    for (int j = 0; j < 2; j++) {
      acc1[i][j] = (f32x4){0.f, 0.f, 0.f, 0.f};
      acc2[i][j] = (f32x4){0.f, 0.f, 0.f, 0.f};
    }

  const int KM = K >> 6;            // macro-steps: 16/32/64 — always even
  const int KS1 = Ksplit >> 5;      // split in 32-K substeps (multiple of 2)

  // stage one 64-K macro-step (16 chunks of 1 KB, 4 per wave) into dA
  auto stageA = [&](int km, short* dA) {
    int k032 = km * 2;               // first 32-K substep index
    const short *ph, *pl;
    int kk;
    if (k032 < KS1) { ph = A1h; pl = A1l; kk = k032; }
    else            { ph = A2h; pl = A2l; kk = k032 - KS1; }
    // Ksplit % 64 == 0 -> both substeps in same segment
    size_t base = ((size_t)kk * MCH + (blockM >> 4)) * 512 + lane * 8;
#pragma unroll
    for (int s = 0; s < 4; s++) {
      int g2 = wave * 4 + s;         // 0..15
      int sub = g2 >> 3;             // substep 0/1
      int g = g2 & 7;                // chunk within substep
      int t = g & 3;
      const short* plane = (g < 4) ? ph : pl;
      gld_lds16(plane + base + (sub * MCH + t) * 512, dA + g2 * 512);
    }
  };

  // load B fragments for 32-K substep ks32 into a register set
  auto loadB = [&](int ks32, f16x8* bH, f16x8* bL) {
    size_t base =
        ((size_t)ks32 * (N >> 4) + (blockN >> 4) + wave * 2) * 512 + lane * 8;
    bH[0] = *(const f16x8*)(BTh + base);
    bH[1] = *(const f16x8*)(BTh + base + 512);
    bL[0] = *(const f16x8*)(BTl + base);
    bL[1] = *(const f16x8*)(BTl + base + 512);
  };

  // compute one 32-K substep from LDS sub-buffer + B regs
  auto computeSub = [&](const short* sA, const f16x8* bH, const f16x8* bL) {
    f16x8 aH[4];
#pragma unroll
    for (int t = 0; t < 4; t++)
      aH[t] = *(const f16x8*)&sA[t * 512 + lane * 8];
#pragma unroll
    for (int i = 0; i < 4; i++)
#pragma unroll
      for (int j = 0; j < 2; j++)
        acc1[i][j] = __builtin_amdgcn_mfma_f32_16x16x32_f16(aH[i], bH[j],
                                                            acc1[i][j], 0, 0, 0);
#pragma unroll
    for (int i = 0; i < 4; i++)
#pragma unroll
      for (int j = 0; j < 2; j++)
        acc2[i][j] = __builtin_amdgcn_mfma_f32_16x16x32_f16(aH[i], bL[j],
                                                            acc2[i][j], 0, 0, 0);
    f16x8 aL[4];
#pragma unroll
    for (int t = 0; t < 4; t++)
      aL[t] = *(const f16x8*)&sA[(4 + t) * 512 + lane * 8];
#pragma unroll
    for (int i = 0; i < 4; i++)
#pragma unroll
      for (int j = 0; j < 2; j++)
        acc2[i][j] = __builtin_amdgcn_mfma_f32_16x16x32_f16(aL[i], bH[j],
                                                            acc2[i][j], 0, 0, 0);
  };

  // B register sets: set0 <- even substeps (sub0), set1 <- odd (sub1)
  f16x8 bH0[2], bL0[2], bH1[2], bL1[2];

  // one macro-step: JIT-load B(sub1), compute sub0 (B set0 preloaded),
  // JIT-load next macro's B(sub0), compute sub1.
  auto macro = [&](int km, const short* buf, int kmNextB) {
    loadB(km * 2 + 1, bH1, bL1);
    computeSub(buf, bH0, bL0);
    if (kmNextB >= 0) loadB(kmNextB * 2, bH0, bL0);
    computeSub(buf + 8 * 512, bH1, bL1);
  };

  stageA(0, lA0);
  loadB(0, bH0, bL0);
  __syncthreads();  // prologue drain (full latency once)

  for (int km = 0; km < KM; km += 2) {
    // prefetch macro km+1 (A-DMA), then compute macro km: barrier drain is
    // overlapped by 48 MFMAs + 16 ds_read_b128 of compute.
    stageA(km + 1, lA1);                   // km+1 < KM always (KM even)
    macro(km, lA0, km + 1);
    __syncthreads();
    if (km + 2 < KM) stageA(km + 2, lA0);
    macro(km + 1, lA1, (km + 2 < KM) ? km + 2 : -1);
    __syncthreads();
  }

  // epilogue: combine accs, bias + per-column activation + clip.
  // C/D map col=lane&15, row=quad*4+reg (m89-verified).
  // OUT_F16 path writes PACKED layout (next layer's A).
#pragma unroll
  for (int j = 0; j < 2; j++) {
    int col = blockN + wave * 32 + j * 16 + m16;
    float b = bias[col];
    float m = mo[col];
    int a = aid[col];
    size_t kbase = OUT_F16 ? ((size_t)(col >> 5) * MCH) * 512 +
                                 (size_t)((col >> 3) & 3) * 128 + (col & 7)
                           : 0;
#pragma unroll
    for (int i = 0; i < 4; i++) {
#pragma unroll
      for (int r = 0; r < 4; r++) {
        int row = blockM + i * 16 + quad * 4 + r;
        float s = acc1[i][j][r] + acc2[i][j][r] * INV_LO_SCALE;
        float v = rand_act(s + b, a, m);
        if (OUT_F16) {
          unsigned short h, l;
          split_h(v, h, l);
          size_t pidx = kbase + (size_t)(row >> 4) * 512 + (row & 15) * 8;
          Ch[pidx] = h;
          Cl[pidx] = l;
        } else {
          Cf[(size_t)row * N + col] = v;
        }
      }
    }
  }
}

extern "C" void kernel_launch(void* const* d_in, const int* in_sizes, int n_in,
                              void* d_out, int out_size, void* d_ws,
                              size_t ws_size, hipStream_t stream) {
  (void)in_sizes; (void)n_in; (void)out_size; (void)ws_size;

  const float* x     = (const float*)d_in[0];
  const float* W_in  = (const float*)d_in[1];
  const float* b_in  = (const float*)d_in[2];
  const float* Wh[6] = {(const float*)d_in[3], (const float*)d_in[4],
                        (const float*)d_in[5], (const float*)d_in[6],
                        (const float*)d_in[7], (const float*)d_in[8]};
  const float* bh    = (const float*)d_in[9];
  const float* W_out = (const float*)d_in[10];
  const float* b_out = (const float*)d_in[11];
  const float* mo_in = (const float*)d_in[12];
  const float* mo_h  = (const float*)d_in[13];
  const float* mo_out= (const float*)d_in[14];
  const int* aid_in  = (const int*)d_in[15];
  const int* aid_h   = (const int*)d_in[16];
  const int* aid_out = (const int*)d_in[17];

  const int hin[6] = {XDIM, XDIM, 2 * XDIM, XDIM, 2 * XDIM, XDIM};

  // workspace layout (~264 MB); each tensor = hi plane then lo plane (packed)
  char* p = (char*)d_ws;
  auto take = [&](size_t elems) {
    short* q = (short*)p;
    p += elems * 2 * 2;  // hi + lo, 2B each
    return q;
  };
  short* x_s = take((size_t)BDIM * INDIM);
  size_t xpl = (size_t)BDIM * INDIM;
  short* w_in_s = take((size_t)XDIM * INDIM);
  size_t wpl_in = (size_t)XDIM * INDIM;
  short* w_h_s[6];
  size_t wpl_h[6];
  for (int i = 0; i < 6; i++) {
    wpl_h[i] = (size_t)XDIM * hin[i];
    w_h_s[i] = take(wpl_h[i]);
  }
  short* w_out_s = take((size_t)OUTDIM * XDIM);
  size_t wpl_out = (size_t)OUTDIM * XDIM;
  const size_t apl = (size_t)BDIM * XDIM;  // activation plane
  short* actA = take(apl);
  short* actB = take(apl);
  short* actC = take(apl);

  // 1) pack x -> hi/lo fp16 packed
  pack_x<<<dim3(INDIM / 32, BDIM / 64), dim3(256), 0, stream>>>(
      x, (unsigned short*)x_s, (unsigned short*)(x_s + xpl), INDIM);
  // 2) pack all weights: W(K,N) -> packed BT(rows=N, Kdim=K) hi/lo
  pack_w<<<dim3(XDIM / 32, INDIM / 32), dim3(32, 8), 0, stream>>>(
      W_in, (unsigned short*)w_in_s, (unsigned short*)(w_in_s + wpl_in), INDIM,
      XDIM);
  for (int i = 0; i < 6; i++)
    pack_w<<<dim3(XDIM / 32, hin[i] / 32), dim3(32, 8), 0, stream>>>(
        Wh[i], (unsigned short*)w_h_s[i],
        (unsigned short*)(w_h_s[i] + wpl_h[i]), hin[i], XDIM);
  pack_w<<<dim3(OUTDIM / 32, XDIM / 32), dim3(32, 8), 0, stream>>>(
      W_out, (unsigned short*)w_out_s, (unsigned short*)(w_out_s + wpl_out),
      XDIM, OUTDIM);

  // 3) GEMM chain with 3 rotating activation buffers
  auto G = [&](const short* A1, size_t a1pl, const short* A2, size_t a2pl,
               const short* W, size_t wpl, const float* bi, const float* m,
               const int* a, short* Cb, float* Cf, int N, int K, int Ks) {
    dim3 grid(N / 128, BDIM / 64);
    const short* A2h = A2;
    const short* A2l = A2 ? A2 + a2pl : nullptr;
    if (Cb)
      gemm_split_act<true><<<grid, 256, 0, stream>>>(
          A1, A1 + a1pl, A2h, A2l, W, W + wpl, bi, m, a, (unsigned short*)Cb,
          (unsigned short*)(Cb + apl), nullptr, N, K, Ks);
    else
      gemm_split_act<false><<<grid, 256, 0, stream>>>(
          A1, A1 + a1pl, A2h, A2l, W, W + wpl, bi, m, a, nullptr, nullptr, Cf,
          N, K, Ks);
  };

  // input layer: outs[0]=actA
  G(x_s, xpl, nullptr, 0, w_in_s, wpl_in, b_in, mo_in, aid_in, actA, nullptr,
    XDIM, INDIM, INDIM);
  // L0: outs[1]=actB
  G(actA, apl, nullptr, 0, w_h_s[0], wpl_h[0], bh + 0 * XDIM, mo_h + 0 * XDIM,
    aid_h + 0 * XDIM, actB, nullptr, XDIM, XDIM, XDIM);
  // L1: outs[2]=actC
  G(actB, apl, nullptr, 0, w_h_s[1], wpl_h[1], bh + 1 * XDIM, mo_h + 1 * XDIM,
    aid_h + 1 * XDIM, actC, nullptr, XDIM, XDIM, XDIM);
  // L2 (concat outs2,outs1): outs[3]=actA
  G(actC, apl, actB, apl, w_h_s[2], wpl_h[2], bh + 2 * XDIM, mo_h + 2 * XDIM,
    aid_h + 2 * XDIM, actA, nullptr, XDIM, 2 * XDIM, XDIM);
  // L3: outs[4]=actB
  G(actA, apl, nullptr, 0, w_h_s[3], wpl_h[3], bh + 3 * XDIM, mo_h + 3 * XDIM,
    aid_h + 3 * XDIM, actB, nullptr, XDIM, XDIM, XDIM);
  // L4 (concat outs4,outs3): outs[5]=actC
  G(actB, apl, actA, apl, w_h_s[4], wpl_h[4], bh + 4 * XDIM, mo_h + 4 * XDIM,
    aid_h + 4 * XDIM, actC, nullptr, XDIM, 2 * XDIM, XDIM);
  // L5: outs[6]=actB
  G(actC, apl, nullptr, 0, w_h_s[5], wpl_h[5], bh + 5 * XDIM, mo_h + 5 * XDIM,
    aid_h + 5 * XDIM, actB, nullptr, XDIM, XDIM, XDIM);
  // output layer -> d_out (fp32, row-major)
  G(actB, apl, nullptr, 0, w_out_s, wpl_out, b_out, mo_out, aid_out, nullptr,
    (float*)d_out, OUTDIM, XDIM, XDIM);
}